// Round 10
// baseline (329.395 us; speedup 1.0000x reference)
//
#include <hip/hip_runtime.h>

#define KNN 16
#define FSEM 32
#define LPG 4                 // lanes cooperating per gaussian
#define GPB 64                // gaussians per main block (256/LPG)
#define MAXT 64               // max supported T for sort path
#define HBLK 1024             // hist/scatter block size

__device__ __forceinline__ float sigmoidf_(float x) { return 1.0f / (1.0f + __expf(-x)); }

// q / clip(|q|,1e-12) -> row-major 3x3
__device__ __forceinline__ void quat_to_R(float qw, float qx, float qy, float qz, float* R) {
    float d = qw * qw + qx * qx + qy * qy + qz * qz;
    float inv = rsqrtf(fmaxf(d, 1e-24f));
    float w = qw * inv, x = qx * inv, y = qy * inv, z = qz * inv;
    R[0] = 1.f - 2.f * (y * y + z * z); R[1] = 2.f * (x * y - w * z); R[2] = 2.f * (x * z + w * y);
    R[3] = 2.f * (x * y + w * z); R[4] = 1.f - 2.f * (x * x + z * z); R[5] = 2.f * (y * z - w * x);
    R[6] = 2.f * (x * z - w * y); R[7] = 2.f * (y * z + w * x); R[8] = 1.f - 2.f * (x * x + y * y);
}

// ---- prepack: packed[p] = {x,y,z,pad, qw,qx,qy,qz} (32 B, never straddles a line) ----
__global__ void __launch_bounds__(256)
k_pack(const float* __restrict__ node_xyz, const float* __restrict__ node_quat,
       float* __restrict__ packed, int TM)
{
    int p = blockIdx.x * blockDim.x + threadIdx.x;
    if (p >= TM) return;
    const float* x = node_xyz + 3 * (size_t)p;
    float4 a = make_float4(x[0], x[1], x[2], 0.f);
    float4 q = reinterpret_cast<const float4*>(node_quat)[p];
    float4* dst = reinterpret_cast<float4*>(packed + 8 * (size_t)p);
    dst[0] = a;
    dst[1] = q;
}

// ---- counting sort by ref_time, atomic-free at global scope ----
__global__ void __launch_bounds__(HBLK)
k_hist(const int* __restrict__ ref_time, int* __restrict__ cnt, int N, int T, int NB)
{
    __shared__ int h[MAXT];
    if (threadIdx.x < T) h[threadIdx.x] = 0;
    __syncthreads();
    int n = blockIdx.x * HBLK + threadIdx.x;
    if (n < N) atomicAdd(&h[ref_time[n]], 1);
    __syncthreads();
    if (threadIdx.x < T) cnt[(size_t)threadIdx.x * NB + blockIdx.x] = h[threadIdx.x];
}

// one block of 256 (4 waves). Produces off[b][nb] (global perm start for block nb of
// bucket b), total[b], base[b] (bucket start in perm), nbb[b] (main blocks per bucket),
// bstart[b] (per-XCD-class block-slot start).
__global__ void __launch_bounds__(256)
k_scan(int* __restrict__ cnt, int* __restrict__ off, int* __restrict__ total,
       int* __restrict__ base, int* __restrict__ nbb, int* __restrict__ bstart,
       int T, int NB)
{
    const int lane = threadIdx.x & 63;
    const int w    = threadIdx.x >> 6;
    for (int b = w; b < T; b += 4) {
        int carry = 0;
        for (int base0 = 0; base0 < NB; base0 += 64) {
            int idx = base0 + lane;
            int v0 = (idx < NB) ? cnt[(size_t)b * NB + idx] : 0;
            int v = v0;
#pragma unroll
            for (int d = 1; d < 64; d <<= 1) {
                int tt = __shfl_up(v, d);
                if (lane >= d) v += tt;
            }
            if (idx < NB) off[(size_t)b * NB + idx] = carry + v - v0;
            carry += __shfl(v, 63);
        }
        if (lane == 0) total[b] = carry;
    }
    __syncthreads();
    if (threadIdx.x == 0) {
        int run = 0;
        int run8[8] = {0,0,0,0,0,0,0,0};
        for (int b = 0; b < T; b++) {
            base[b] = run; run += total[b];
            int nb = (total[b] + GPB - 1) / GPB;
            nbb[b] = nb;
            int x = b & 7;
            bstart[b] = run8[x];
            run8[x] += nb;
        }
    }
    __syncthreads();
    for (int i = threadIdx.x; i < T * NB; i += blockDim.x) {
        int b = i / NB;
        off[i] += base[b];
    }
}

__global__ void __launch_bounds__(HBLK)
k_scatter(const int* __restrict__ ref_time, const int* __restrict__ attach,
          const int* __restrict__ off, int2* __restrict__ perm2, int N, int T, int NB)
{
    __shared__ int h[MAXT];
    if (threadIdx.x < T) h[threadIdx.x] = 0;
    __syncthreads();
    int n = blockIdx.x * HBLK + threadIdx.x;
    if (n < N) {
        int rt = ref_time[n];
        int rank = atomicAdd(&h[rt], 1);              // LDS only
        int pos = off[(size_t)rt * NB + blockIdx.x] + rank;
        perm2[pos] = make_int2(n, attach[n]);
    }
}

// ---- elementwise outputs in natural (coalesced) order: s, o, sph ----
__global__ void __launch_bounds__(256)
k_elem(const float* __restrict__ gs_scal,
       const float* __restrict__ gs_opa,
       const float* __restrict__ feat_dc,
       const float* __restrict__ feat_rest,
       float* __restrict__ out, int N)
{
    const int n = blockIdx.x * blockDim.x + threadIdx.x;
    if (n >= N) return;
    const size_t Ns = (size_t)N, ns = (size_t)n;

    float* os = out + 12 * Ns + 3 * ns;
    os[0] = 0.1f * sigmoidf_(gs_scal[3 * ns + 0]);
    os[1] = 0.1f * sigmoidf_(gs_scal[3 * ns + 1]);
    os[2] = 0.1f * sigmoidf_(gs_scal[3 * ns + 2]);

    out[15 * Ns + ns] = sigmoidf_(gs_opa[ns]);

    float* osph = out + 16 * Ns + 12 * ns;   // 16B-aligned
    float4 v0 = make_float4(feat_dc[3 * ns + 0], feat_dc[3 * ns + 1], feat_dc[3 * ns + 2],
                            feat_rest[9 * ns + 0]);
    float4 v1 = make_float4(feat_rest[9 * ns + 1], feat_rest[9 * ns + 2],
                            feat_rest[9 * ns + 3], feat_rest[9 * ns + 4]);
    float4 v2 = make_float4(feat_rest[9 * ns + 5], feat_rest[9 * ns + 6],
                            feat_rest[9 * ns + 7], feat_rest[9 * ns + 8]);
    reinterpret_cast<float4*>(osph)[0] = v0;
    reinterpret_cast<float4*>(osph)[1] = v1;
    reinterpret_cast<float4*>(osph)[2] = v2;
}

// ---- shared skinning body (packed node data) ----
__device__ __forceinline__ void
skin_body(int n, int a, int rt, int sub, int t,
          const float* __restrict__ gs_xyz, const float* __restrict__ gs_rot,
          const float* __restrict__ packed, const float* __restrict__ node_sigma,
          const float* __restrict__ node_sem, const int* __restrict__ topo_knn,
          float* __restrict__ out, int N, int M)
{
    const size_t base_rt = (size_t)rt * (size_t)M;
    const size_t base_t  = (size_t)t  * (size_t)M;

    const float4* pk = reinterpret_cast<const float4*>(packed + (base_rt + (size_t)a) * 8);
    float4 axz = pk[0], aqv = pk[1];
    float Rref[9];
    quat_to_R(aqv.x, aqv.y, aqv.z, aqv.w, Rref);

    const float gx = gs_xyz[3 * (size_t)n + 0];
    const float gy = gs_xyz[3 * (size_t)n + 1];
    const float gz = gs_xyz[3 * (size_t)n + 2];

    const float xw0 = Rref[0] * gx + Rref[1] * gy + Rref[2] * gz + axz.x;
    const float xw1 = Rref[3] * gx + Rref[4] * gy + Rref[5] * gz + axz.y;
    const float xw2 = Rref[6] * gx + Rref[7] * gy + Rref[8] * gz + axz.z;

    const int4 kv = reinterpret_cast<const int4*>(topo_knn)[(size_t)a * (KNN / 4) + sub];
    const int js[4] = { kv.x, kv.y, kv.z, kv.w };

    float wsum = 0.f, mu0 = 0.f, mu1 = 0.f, mu2 = 0.f;
    float qb0 = 0.f, qb1 = 0.f, qb2 = 0.f, qb3 = 0.f;
    float sem[FSEM];
#pragma unroll
    for (int f = 0; f < FSEM; f++) sem[f] = 0.f;

#pragma unroll
    for (int k = 0; k < KNN / LPG; k++) {
        const int j = js[k];

        const float4* pkr = reinterpret_cast<const float4*>(packed + (base_rt + (size_t)j) * 8);
        float4 xr = pkr[0], qr = pkr[1];
        const float4* pkl = reinterpret_cast<const float4*>(packed + (base_t + (size_t)j) * 8);
        float4 xl = pkl[0], ql = pkl[1];

        const float dx = xw0 - xr.x;
        const float dy = xw1 - xr.y;
        const float dz = xw2 - xr.z;
        const float dsq = dx * dx + dy * dy + dz * dz;

        const float sg = node_sigma[j];
        const float w = __expf(-dsq / (2.f * sg * sg + 1e-8f));

        float rw = qr.x, rx = qr.y, ry = qr.z, rz = qr.w;
        {
            float inv = rsqrtf(fmaxf(rw * rw + rx * rx + ry * ry + rz * rz, 1e-24f));
            rw *= inv; rx *= inv; ry *= inv; rz *= inv;
        }
        float lw = ql.x, lx = ql.y, ly = ql.z, lz = ql.w;
        {
            float inv = rsqrtf(fmaxf(lw * lw + lx * lx + ly * ly + lz * lz, 1e-24f));
            lw *= inv; lx *= inv; ly *= inv; lz *= inv;
        }
        const float qw =  lw * rw + lx * rx + ly * ry + lz * rz;
        const float qx = -lw * rx + lx * rw - ly * rz + lz * ry;
        const float qy = -lw * ry + lx * rz + ly * rw - lz * rx;
        const float qz = -lw * rz - lx * ry + ly * rx + lz * rw;

        float Rr[9];
        quat_to_R(qw, qx, qy, qz, Rr);

        const float m0 = Rr[0] * dx + Rr[1] * dy + Rr[2] * dz + xl.x;
        const float m1 = Rr[3] * dx + Rr[4] * dy + Rr[5] * dz + xl.y;
        const float m2 = Rr[6] * dx + Rr[7] * dy + Rr[8] * dz + xl.z;

        wsum += w;
        mu0 += w * m0; mu1 += w * m1; mu2 += w * m2;
        qb0 += w * qw; qb1 += w * qx; qb2 += w * qy; qb3 += w * qz;

        const float4* sp4 = reinterpret_cast<const float4*>(node_sem + (size_t)j * FSEM);
#pragma unroll
        for (int q = 0; q < 8; q++) {
            float4 v = sp4[q];
            sem[q * 4 + 0] += w * v.x;
            sem[q * 4 + 1] += w * v.y;
            sem[q * 4 + 2] += w * v.z;
            sem[q * 4 + 3] += w * v.w;
        }
    }

#pragma unroll
    for (int m = 1; m < LPG; m <<= 1) {
        wsum += __shfl_xor(wsum, m);
        mu0  += __shfl_xor(mu0, m);  mu1 += __shfl_xor(mu1, m);  mu2 += __shfl_xor(mu2, m);
        qb0  += __shfl_xor(qb0, m);  qb1 += __shfl_xor(qb1, m);
        qb2  += __shfl_xor(qb2, m);  qb3 += __shfl_xor(qb3, m);
#pragma unroll
        for (int f = 0; f < FSEM; f++) sem[f] += __shfl_xor(sem[f], m);
    }

    const float invw = 1.f / (wsum + 1e-8f);
    const size_t Ns = (size_t)N, ns = (size_t)n;

    if (sub == 0) {
        out[3 * ns + 0] = mu0 * invw;
        out[3 * ns + 1] = mu1 * invw;
        out[3 * ns + 2] = mu2 * invw;
    } else if (sub == 1) {
        // fr_live = q2R(qb*invw) @ (Rref @ q2R(gs_rot)); invw BEFORE q2R (fp32
        // subnormal guard — r5 bug).
        const float4 qg = *reinterpret_cast<const float4*>(gs_rot + 4 * ns);
        float Rg[9];
        quat_to_R(qg.x, qg.y, qg.z, qg.w, Rg);
        float Rw[9];
#pragma unroll
        for (int i = 0; i < 3; i++)
#pragma unroll
            for (int j = 0; j < 3; j++)
                Rw[3 * i + j] = Rref[3 * i] * Rg[j] + Rref[3 * i + 1] * Rg[3 + j] + Rref[3 * i + 2] * Rg[6 + j];
        float Rb[9];
        quat_to_R(qb0 * invw, qb1 * invw, qb2 * invw, qb3 * invw, Rb);
        float* ofr = out + 3 * Ns + 9 * ns;
#pragma unroll
        for (int i = 0; i < 3; i++)
#pragma unroll
            for (int j = 0; j < 3; j++)
                ofr[3 * i + j] = Rb[3 * i] * Rw[j] + Rb[3 * i + 1] * Rw[3 + j] + Rb[3 * i + 2] * Rw[6 + j];
    }

    float4* osem = reinterpret_cast<float4*>(out + 28 * Ns + FSEM * ns);
#pragma unroll
    for (int q = 0; q < 2; q++) {
        const int b = sub * 2 + q;
        osem[b] = make_float4(sem[4 * b + 0] * invw, sem[4 * b + 1] * invw,
                              sem[4 * b + 2] * invw, sem[4 * b + 3] * invw);
    }
}

// ---- sorted main: bucket (=rt) pinned to XCD class via blockIdx%8 ----
__global__ void __launch_bounds__(256)
dynscf_sorted(const float* __restrict__ gs_xyz,
              const float* __restrict__ gs_rot,
              const float* __restrict__ packed,
              const float* __restrict__ node_sigma,
              const float* __restrict__ node_sem,
              const int* __restrict__ topo_knn,
              const int* __restrict__ t_ptr,
              const int* __restrict__ total,
              const int* __restrict__ base,
              const int* __restrict__ nbb,
              const int* __restrict__ bstart,
              const int2* __restrict__ perm2,
              float* __restrict__ out,
              int N, int M, int T)
{
    const int x = blockIdx.x & 7;
    const int s = blockIdx.x >> 3;
    int b = -1, sl = 0;
    for (int bb = x; bb < T; bb += 8) {
        const int bs = bstart[bb];
        if (s < bs) break;
        if (s < bs + nbb[bb]) { b = bb; sl = s - bs; break; }
    }
    if (b < 0) return;

    const int gib = sl * GPB + ((int)threadIdx.x >> 2);
    if (gib >= total[b]) return;

    const int2 pa = perm2[(size_t)base[b] + gib];
    skin_body(pa.x, pa.y, b, threadIdx.x & 3, t_ptr[0],
              gs_xyz, gs_rot, packed, node_sigma, node_sem, topo_knn, out, N, M);
}

// ---- unsorted fallback (r9 path) ----
__global__ void __launch_bounds__(256)
dynscf_plain(const float* __restrict__ gs_xyz,
             const float* __restrict__ gs_rot,
             const float* __restrict__ packed,
             const float* __restrict__ node_sigma,
             const float* __restrict__ node_sem,
             const int* __restrict__ attach_ind,
             const int* __restrict__ ref_time,
             const int* __restrict__ topo_knn,
             const int* __restrict__ t_ptr,
             float* __restrict__ out,
             int N, int M)
{
    const int tid = blockIdx.x * blockDim.x + threadIdx.x;
    const int n = tid >> 2;
    if (n >= N) return;
    skin_body(n, attach_ind[n], ref_time[n], tid & 3, t_ptr[0],
              gs_xyz, gs_rot, packed, node_sigma, node_sem, topo_knn, out, N, M);
}

extern "C" void kernel_launch(void* const* d_in, const int* in_sizes, int n_in,
                              void* d_out, int out_size, void* d_ws, size_t ws_size,
                              hipStream_t stream)
{
    const float* gs_xyz     = (const float*)d_in[0];
    const float* gs_rot     = (const float*)d_in[1];
    const float* gs_scal    = (const float*)d_in[2];
    const float* gs_opa     = (const float*)d_in[3];
    const float* feat_dc    = (const float*)d_in[4];
    const float* feat_rest  = (const float*)d_in[5];
    const float* node_xyz   = (const float*)d_in[6];
    const float* node_quat  = (const float*)d_in[7];
    const float* node_sigma = (const float*)d_in[8];
    const float* node_sem   = (const float*)d_in[9];
    const int* attach_ind   = (const int*)d_in[10];
    const int* ref_time     = (const int*)d_in[11];
    const int* topo_knn     = (const int*)d_in[12];
    const int* t_ptr        = (const int*)d_in[13];

    const int N  = in_sizes[0] / 3;
    const int M  = in_sizes[8];            // node_sigma is (M,1)
    const int TM = in_sizes[6] / 3;        // T*M
    const int T  = TM / M;

    float* out = (float*)d_out;

    const int block = 256;
    const int gridN = (N + block - 1) / block;
    const int NB    = (N + HBLK - 1) / HBLK;

    // ws layout (ints): cnt[T*NB] | off[T*NB] | total[64] base[64] nbb[64] bstart[64]
    // then perm2 (int2, 8B aligned), then packed (16B aligned).
    size_t meta_ints = (size_t)2 * T * NB + 4 * MAXT;
    if (meta_ints & 1) meta_ints++;
    const size_t perm_off   = meta_ints * sizeof(int);
    const size_t packed_off = (perm_off + (size_t)N * 8 + 15) & ~(size_t)15;
    const size_t need_sort  = packed_off + (size_t)TM * 32;
    const size_t need_pack  = (size_t)TM * 32;

    const bool can_sort = (T <= MAXT) && (ws_size >= need_sort);
    const bool can_pack = (ws_size >= need_pack);

    if (can_sort) {
        int* cnt    = (int*)d_ws;
        int* off    = cnt + (size_t)T * NB;
        int* total  = off + (size_t)T * NB;
        int* basep  = total + MAXT;
        int* nbb    = basep + MAXT;
        int* bstart = nbb + MAXT;
        int2* perm2 = (int2*)((char*)d_ws + perm_off);
        float* packed = (float*)((char*)d_ws + packed_off);

        const int gridP = (TM + block - 1) / block;
        hipLaunchKernelGGL(k_pack, dim3(gridP), dim3(block), 0, stream,
                           node_xyz, node_quat, packed, TM);
        hipLaunchKernelGGL(k_hist, dim3(NB), dim3(HBLK), 0, stream,
                           ref_time, cnt, N, T, NB);
        hipLaunchKernelGGL(k_scan, dim3(1), dim3(256), 0, stream,
                           cnt, off, total, basep, nbb, bstart, T, NB);
        hipLaunchKernelGGL(k_scatter, dim3(NB), dim3(HBLK), 0, stream,
                           ref_time, attach_ind, off, perm2, N, T, NB);

        const int slots = (N + GPB - 1) / GPB + T;   // worst-case per XCD class
        hipLaunchKernelGGL(dynscf_sorted, dim3(8 * slots), dim3(block), 0, stream,
                           gs_xyz, gs_rot, packed, node_sigma, node_sem, topo_knn,
                           t_ptr, total, basep, nbb, bstart, perm2, out, N, M, T);
    } else if (can_pack) {
        float* packed = (float*)d_ws;
        const int gridP = (TM + block - 1) / block;
        const int gridM = (int)(((long long)N * LPG + block - 1) / block);
        hipLaunchKernelGGL(k_pack, dim3(gridP), dim3(block), 0, stream,
                           node_xyz, node_quat, packed, TM);
        hipLaunchKernelGGL(dynscf_plain, dim3(gridM), dim3(block), 0, stream,
                           gs_xyz, gs_rot, packed, node_sigma, node_sem,
                           attach_ind, ref_time, topo_knn, t_ptr, out, N, M);
    }
    // (ws too small for even packing is not expected on this harness)

    hipLaunchKernelGGL(k_elem, dim3(gridN), dim3(block), 0, stream,
                       gs_scal, gs_opa, feat_dc, feat_rest, out, N);
}